// Round 1
// baseline (362.773 us; speedup 1.0000x reference)
//
#include <hip/hip_runtime.h>

typedef unsigned short u16;
typedef unsigned int u32;
typedef __attribute__((ext_vector_type(8))) short short8;   // 8 bf16 (4 VGPRs)
typedef __attribute__((ext_vector_type(4))) float floatx4;  // MFMA accumulator

__device__ __forceinline__ u16 f2bf(float f) {
  u32 u = __float_as_uint(f);
  u32 r = u + 0x7fffu + ((u >> 16) & 1u);   // round-to-nearest-even
  return (u16)(r >> 16);
}

// async global->LDS, 16B per lane. lds ptr must be wave-uniform base; HW
// writes lane i at base + i*16.
__device__ __forceinline__ void gload_lds16(const u16* g, u16* l) {
  __builtin_amdgcn_global_load_lds(
      (const __attribute__((address_space(1))) u32*)g,
      (__attribute__((address_space(3))) u32*)l, 16, 0, 0);
}

// ---------------------------------------------------------------------------
// Fused cast (fp32->bf16) + transpose. in: [rows, cols] fp32 (per batch).
// cast_out (optional): bf16 same layout. tr_out: bf16 [cols, rows].
// ---------------------------------------------------------------------------
__global__ __launch_bounds__(256)
void cast_tr(const float* __restrict__ in, u16* __restrict__ cast_out,
             u16* __restrict__ tr_out, int rows, int cols, float scale,
             long bstride)
{
  __shared__ u16 tile[64][65];
  const int b = blockIdx.z;
  in += (long)b * bstride;
  if (cast_out) cast_out += (long)b * bstride;
  tr_out += (long)b * bstride;
  const int r0 = blockIdx.y * 64, c0 = blockIdx.x * 64;
  const int tx = threadIdx.x & 63, ty = threadIdx.x >> 6;

  for (int i = ty; i < 64; i += 4) {
    float v = in[(long)(r0 + i) * cols + c0 + tx] * scale;
    u16 h = f2bf(v);
    if (cast_out) cast_out[(long)(r0 + i) * cols + c0 + tx] = h;
    tile[i][tx] = h;
  }
  __syncthreads();
  for (int i = ty; i < 64; i += 4)
    tr_out[(long)(c0 + i) * rows + r0 + tx] = tile[tx][i];
}

// ---------------------------------------------------------------------------
// NT GEMM: C[M,N] = A[M,K] * Bt[N,K]^T, bf16 inputs, fp32 accumulate.
// 128x128 tile, BK=64, 4 waves in 2x2, each wave 4x4 tiles of 16x16x32 MFMA.
// LDS staged via global_load_lds(16B) with XOR chunk swizzle:
//   LDS[r][chunk c] holds global chunk (c ^ (r&7))  -> ds_read_b128 conflict-free.
// ---------------------------------------------------------------------------
#define BM 128
#define BN 128
#define BK 64

template<bool BF16_OUT>
__global__ __launch_bounds__(256, 3)
void gemm_nt(const u16* __restrict__ A, const u16* __restrict__ Bt,
             void* __restrict__ Cout, const float* __restrict__ bias,
             int M, int N, int K, int lda, int ldb, int ldc,
             long sA, long sB, long sC)
{
  __shared__ __align__(16) u16 As[BM * BK];
  __shared__ __align__(16) u16 Bs[BN * BK];

  const int bz = blockIdx.z;
  A  += (long)bz * sA;
  Bt += (long)bz * sB;

  const int tid  = threadIdx.x;
  const int wave = tid >> 6;
  const int lane = tid & 63;

  const int tileM = blockIdx.y * BM;
  const int tileN = blockIdx.x * BN;

  // staging: per instruction a wave covers 8 rows x 8 chunks (16B each)
  const int srow = lane >> 3;      // 0..7 row within 8-row group
  const int sj   = lane & 7;       // 0..7 dest chunk
  const int sjj  = sj ^ srow;      // swizzled source chunk

  // wave quadrant + mfma lane coords
  const int wm = (wave >> 1) * 64;
  const int wn = (wave & 1) * 64;
  const int lc = lane & 15;        // A row / B col / C col
  const int lq = lane >> 4;        // quad

  floatx4 acc[4][4];
  #pragma unroll
  for (int i = 0; i < 4; ++i)
    #pragma unroll
    for (int j = 0; j < 4; ++j)
      acc[i][j] = (floatx4){0.f, 0.f, 0.f, 0.f};

  for (int k0 = 0; k0 < K; k0 += BK) {
    #pragma unroll
    for (int s = 0; s < 4; ++s) {
      const int rb = wave * 32 + s * 8;     // row-group base within tile
      gload_lds16(A  + (long)(tileM + rb + srow) * lda + k0 + sjj * 8,
                  &As[rb * BK]);
      gload_lds16(Bt + (long)(tileN + rb + srow) * ldb + k0 + sjj * 8,
                  &Bs[rb * BK]);
    }
    __syncthreads();   // drains vmcnt(0) -> LDS valid

    #pragma unroll
    for (int kk = 0; kk < BK; kk += 32) {
      const int jcb = (kk >> 3) + lq;       // logical chunk for this quad
      short8 af[4], bf[4];
      #pragma unroll
      for (int i = 0; i < 4; ++i) {
        const int m = wm + i * 16 + lc;
        af[i] = *(const short8*)&As[m * BK + ((jcb ^ (m & 7)) << 3)];
      }
      #pragma unroll
      for (int j = 0; j < 4; ++j) {
        const int n = wn + j * 16 + lc;
        bf[j] = *(const short8*)&Bs[n * BK + ((jcb ^ (n & 7)) << 3)];
      }
      #pragma unroll
      for (int i = 0; i < 4; ++i)
        #pragma unroll
        for (int j = 0; j < 4; ++j)
          acc[i][j] = __builtin_amdgcn_mfma_f32_16x16x32_bf16(
                          af[i], bf[j], acc[i][j], 0, 0, 0);
    }
    __syncthreads();   // protect LDS before next stage
  }

  // epilogue: C/D layout col = lane&15, row = quad*4 + reg
  if (BF16_OUT) {
    u16* C = (u16*)Cout + (long)bz * sC;
    #pragma unroll
    for (int i = 0; i < 4; ++i) {
      const int rb = tileM + wm + i * 16 + lq * 4;
      #pragma unroll
      for (int j = 0; j < 4; ++j) {
        const int col = tileN + wn + j * 16 + lc;
        #pragma unroll
        for (int r = 0; r < 4; ++r)
          C[(long)(rb + r) * ldc + col] = f2bf(acc[i][j][r]);
      }
    }
  } else {
    float* C = (float*)Cout + (long)bz * sC;
    #pragma unroll
    for (int i = 0; i < 4; ++i) {
      const int rb = tileM + wm + i * 16 + lq * 4;
      #pragma unroll
      for (int j = 0; j < 4; ++j) {
        const int col = tileN + wn + j * 16 + lc;
        const float bv = bias ? bias[col] : 0.f;
        #pragma unroll
        for (int r = 0; r < 4; ++r)
          C[(long)(rb + r) * ldc + col] = acc[i][j][r] + bv;
      }
    }
  }
}

// ---------------------------------------------------------------------------
// Row softmax in-place over bf16 [nrows, ncol=2048], one 256-thread block/row.
// ---------------------------------------------------------------------------
__global__ __launch_bounds__(256)
void softmax_rows(u16* __restrict__ S, int ncol)
{
  __shared__ float redmax[4];
  __shared__ float redsum[4];
  const long row = blockIdx.x;
  u16* p = S + row * (long)ncol;
  const int t = threadIdx.x;
  const int lane = t & 63, wave = t >> 6;

  uint4 raw = ((const uint4*)p)[t];   // 8 bf16
  float v[8];
  v[0] = __uint_as_float(raw.x << 16); v[1] = __uint_as_float(raw.x & 0xffff0000u);
  v[2] = __uint_as_float(raw.y << 16); v[3] = __uint_as_float(raw.y & 0xffff0000u);
  v[4] = __uint_as_float(raw.z << 16); v[5] = __uint_as_float(raw.z & 0xffff0000u);
  v[6] = __uint_as_float(raw.w << 16); v[7] = __uint_as_float(raw.w & 0xffff0000u);

  float m = v[0];
  #pragma unroll
  for (int i = 1; i < 8; ++i) m = fmaxf(m, v[i]);
  #pragma unroll
  for (int off = 32; off > 0; off >>= 1) m = fmaxf(m, __shfl_xor(m, off, 64));
  if (lane == 0) redmax[wave] = m;
  __syncthreads();
  m = fmaxf(fmaxf(redmax[0], redmax[1]), fmaxf(redmax[2], redmax[3]));

  float s = 0.f;
  #pragma unroll
  for (int i = 0; i < 8; ++i) { v[i] = __expf(v[i] - m); s += v[i]; }
  #pragma unroll
  for (int off = 32; off > 0; off >>= 1) s += __shfl_xor(s, off, 64);
  if (lane == 0) redsum[wave] = s;
  __syncthreads();
  s = redsum[0] + redsum[1] + redsum[2] + redsum[3];
  const float inv = 1.0f / s;

  uint4 o;
  o.x = (u32)f2bf(v[0]*inv) | ((u32)f2bf(v[1]*inv) << 16);
  o.y = (u32)f2bf(v[2]*inv) | ((u32)f2bf(v[3]*inv) << 16);
  o.z = (u32)f2bf(v[4]*inv) | ((u32)f2bf(v[5]*inv) << 16);
  o.w = (u32)f2bf(v[6]*inv) | ((u32)f2bf(v[7]*inv) << 16);
  ((uint4*)p)[t] = o;
}

// ---------------------------------------------------------------------------
extern "C" void kernel_launch(void* const* d_in, const int* in_sizes, int n_in,
                              void* d_out, int out_size, void* d_ws, size_t ws_size,
                              hipStream_t stream) {
  const float* x    = (const float*)d_in[0];   // [B,S,D] fp32
  const float* W    = (const float*)d_in[1];   // [D,D]   fp32
  const float* bias = (const float*)d_in[2];   // [D]     fp32
  float* out        = (float*)d_out;           // [B,S,D] fp32
  (void)in_sizes; (void)n_in; (void)out_size; (void)ws_size;

  const int B = 8, S = 2048, D = 1024;
  const long BSD = (long)B * S * D;            // 16,777,216

  // workspace layout (u16 elements): total ~162 MB
  u16* Xb  = (u16*)d_ws;            // [B,S,D] bf16 (x)
  u16* XbT = Xb  + BSD;             // [B,D,S] bf16 (x transposed per batch)
  u16* Qb  = XbT + BSD;             // [B,S,D] bf16 (Q, pre-scaled by 1/32)
  u16* Wt  = Qb  + BSD;             // [D,D]   bf16 (W^T * 1/sqrt(D))
  u16* Sc  = Wt  + (long)D * D;     // [B,S,S] bf16 (scores -> probs in place)

  dim3 blk(256);

  // x -> Xb + XbT (scale 1), W -> Wt (scale 1/32 folded into Q)
  cast_tr<<<dim3(D/64, S/64, B), blk, 0, stream>>>(x, Xb, XbT, S, D, 1.0f, (long)S*D);
  cast_tr<<<dim3(D/64, D/64, 1), blk, 0, stream>>>(W, nullptr, Wt, D, D, 0.03125f, 0);

  // GEMM1: Qb[BS,D] = Xb[BS,D] @ Wt[D,D]^T   (batches flattened)
  gemm_nt<true><<<dim3(D/128, (B*S)/128, 1), blk, 0, stream>>>(
      Xb, Wt, Qb, nullptr, B*S, D, D, D, D, D, 0, 0, 0);

  // GEMM2: Sc[S,S] = Qb[S,D] @ Xb[S,D]^T   per batch
  gemm_nt<true><<<dim3(S/128, S/128, B), blk, 0, stream>>>(
      Qb, Xb, Sc, nullptr, S, S, D, D, D, S,
      (long)S*D, (long)S*D, (long)S*S);

  // softmax rows in place
  softmax_rows<<<dim3(B*S), blk, 0, stream>>>(Sc, S);

  // GEMM3: out[S,D] = P[S,S] @ XbT[D,S]^T + bias   per batch, fp32 out
  gemm_nt<false><<<dim3(D/128, S/128, B), blk, 0, stream>>>(
      Sc, XbT, out, bias, S, D, S, S, S, D,
      (long)S*S, (long)D*S, (long)S*D);
}

// Round 2
// 310.790 us; speedup vs baseline: 1.1673x; 1.1673x over previous
//
#include <hip/hip_runtime.h>

typedef unsigned short u16;
typedef unsigned int u32;
typedef __attribute__((ext_vector_type(8))) short short8;   // 8 bf16 (4 VGPRs)
typedef __attribute__((ext_vector_type(4))) float floatx4;  // MFMA accumulator

__device__ __forceinline__ u16 f2bf(float f) {
  u32 u = __float_as_uint(f);
  u32 r = u + 0x7fffu + ((u >> 16) & 1u);   // round-to-nearest-even
  return (u16)(r >> 16);
}

// async global->LDS, 16B per lane. lds ptr must be wave-uniform base; HW
// writes lane i at base + i*16.
__device__ __forceinline__ void gload_lds16(const u16* g, u16* l) {
  __builtin_amdgcn_global_load_lds(
      (const __attribute__((address_space(1))) u32*)g,
      (__attribute__((address_space(3))) u32*)l, 16, 0, 0);
}

// ---------------------------------------------------------------------------
// Fused cast (fp32->bf16) + transpose. in: [rows, cols] fp32 (per batch).
// cast_out (optional): bf16 same layout. tr_out: bf16 [cols, rows].
// ---------------------------------------------------------------------------
__global__ __launch_bounds__(256)
void cast_tr(const float* __restrict__ in, u16* __restrict__ cast_out,
             u16* __restrict__ tr_out, int rows, int cols, float scale,
             long bstride)
{
  __shared__ u16 tile[64][65];
  const int b = blockIdx.z;
  in += (long)b * bstride;
  if (cast_out) cast_out += (long)b * bstride;
  tr_out += (long)b * bstride;
  const int r0 = blockIdx.y * 64, c0 = blockIdx.x * 64;
  const int tx = threadIdx.x & 63, ty = threadIdx.x >> 6;

  for (int i = ty; i < 64; i += 4) {
    float v = in[(long)(r0 + i) * cols + c0 + tx] * scale;
    u16 h = f2bf(v);
    if (cast_out) cast_out[(long)(r0 + i) * cols + c0 + tx] = h;
    tile[i][tx] = h;
  }
  __syncthreads();
  for (int i = ty; i < 64; i += 4)
    tr_out[(long)(c0 + i) * rows + r0 + tx] = tile[tx][i];
}

// ---------------------------------------------------------------------------
// NT GEMM: C[M,N] = A[M,K] * Bt[N,K]^T, bf16 inputs, fp32 accumulate.
// 128x128 tile, BK=64, 4 waves in 2x2, each wave 4x4 tiles of 16x16x32 MFMA.
// LDS staged via global_load_lds(16B) with XOR chunk swizzle.
// GROUP_M=8 block swizzle: consecutive pids walk M within a band of 8 tiles,
// so one B-strip is reused 8x and the live strip set (~4MB) fits an XCD L2.
// MODE 0: plain bf16 out.
// MODE 1: bf16 out = exp(acc); fp32 row sums accumulated into rsum (atomics).
// MODE 2: fp32 out = acc / rsum[row] + bias[col].
// ---------------------------------------------------------------------------
#define BM 128
#define BN 128
#define BK 64

template<int MODE>
__global__ __launch_bounds__(256, 3)
void gemm_nt(const u16* __restrict__ A, const u16* __restrict__ Bt,
             void* __restrict__ Cout, const float* __restrict__ bias,
             float* __restrict__ rsum,
             int M, int N, int K, int lda, int ldb, int ldc,
             long sA, long sB, long sC)
{
  __shared__ __align__(16) u16 As[BM * BK];
  __shared__ __align__(16) u16 Bs[BN * BK];

  const int bz = blockIdx.z;
  A  += (long)bz * sA;
  Bt += (long)bz * sB;

  const int tid  = threadIdx.x;
  const int wave = tid >> 6;
  const int lane = tid & 63;

  // GROUP_M=8 swizzle
  const int nbx = gridDim.x, nby = gridDim.y;
  const int pid  = blockIdx.y * nbx + blockIdx.x;
  const int band = 8 * nbx;
  const int gid  = pid / band;
  const int fm   = gid * 8;
  const int gsz  = min(nby - fm, 8);
  const int pm   = fm + (pid % band) % gsz;
  const int pn   = (pid % band) / gsz;
  const int tileM = pm * BM;
  const int tileN = pn * BN;

  // staging: per instruction a wave covers 8 rows x 8 chunks (16B each)
  const int srow = lane >> 3;      // 0..7 row within 8-row group
  const int sj   = lane & 7;       // 0..7 dest chunk
  const int sjj  = sj ^ srow;      // swizzled source chunk

  // wave quadrant + mfma lane coords
  const int wm = (wave >> 1) * 64;
  const int wn = (wave & 1) * 64;
  const int lc = lane & 15;        // A row / B col / C col
  const int lq = lane >> 4;        // quad

  floatx4 acc[4][4];
  #pragma unroll
  for (int i = 0; i < 4; ++i)
    #pragma unroll
    for (int j = 0; j < 4; ++j)
      acc[i][j] = (floatx4){0.f, 0.f, 0.f, 0.f};

  for (int k0 = 0; k0 < K; k0 += BK) {
    #pragma unroll
    for (int s = 0; s < 4; ++s) {
      const int rb = wave * 32 + s * 8;     // row-group base within tile
      gload_lds16(A  + (long)(tileM + rb + srow) * lda + k0 + sjj * 8,
                  &As[rb * BK]);
      gload_lds16(Bt + (long)(tileN + rb + srow) * ldb + k0 + sjj * 8,
                  &Bs[rb * BK]);
    }
    __syncthreads();   // drains vmcnt(0) -> LDS valid

    #pragma unroll
    for (int kk = 0; kk < BK; kk += 32) {
      const int jcb = (kk >> 3) + lq;       // logical chunk for this quad
      short8 af[4], bf[4];
      #pragma unroll
      for (int i = 0; i < 4; ++i) {
        const int m = wm + i * 16 + lc;
        af[i] = *(const short8*)&As[m * BK + ((jcb ^ (m & 7)) << 3)];
      }
      #pragma unroll
      for (int j = 0; j < 4; ++j) {
        const int n = wn + j * 16 + lc;
        bf[j] = *(const short8*)&Bs[n * BK + ((jcb ^ (n & 7)) << 3)];
      }
      #pragma unroll
      for (int i = 0; i < 4; ++i)
        #pragma unroll
        for (int j = 0; j < 4; ++j)
          acc[i][j] = __builtin_amdgcn_mfma_f32_16x16x32_bf16(
                          af[i], bf[j], acc[i][j], 0, 0, 0);
    }
    __syncthreads();   // protect LDS before next stage
  }

  // epilogue: C/D layout col = lane&15, row = quad*4 + reg
  if (MODE == 0) {
    u16* C = (u16*)Cout + (long)bz * sC;
    #pragma unroll
    for (int i = 0; i < 4; ++i) {
      const int rb = tileM + wm + i * 16 + lq * 4;
      #pragma unroll
      for (int j = 0; j < 4; ++j) {
        const int col = tileN + wn + j * 16 + lc;
        #pragma unroll
        for (int r = 0; r < 4; ++r)
          C[(long)(rb + r) * ldc + col] = f2bf(acc[i][j][r]);
      }
    }
  } else if (MODE == 1) {
    u16* C = (u16*)Cout + (long)bz * sC;
    float* rs = rsum + (long)bz * M;
    #pragma unroll
    for (int i = 0; i < 4; ++i) {
      const int rb = tileM + wm + i * 16 + lq * 4;
      float rpart[4] = {0.f, 0.f, 0.f, 0.f};
      #pragma unroll
      for (int j = 0; j < 4; ++j) {
        const int col = tileN + wn + j * 16 + lc;
        #pragma unroll
        for (int r = 0; r < 4; ++r) {
          float e = __expf(acc[i][j][r]);
          C[(long)(rb + r) * ldc + col] = f2bf(e);
          rpart[r] += e;
        }
      }
      #pragma unroll
      for (int r = 0; r < 4; ++r) {
        float s = rpart[r];
        s += __shfl_xor(s, 1, 64);
        s += __shfl_xor(s, 2, 64);
        s += __shfl_xor(s, 4, 64);
        s += __shfl_xor(s, 8, 64);
        if (lc == 0) atomicAdd(&rs[rb + r], s);
      }
    }
  } else {
    float* C = (float*)Cout + (long)bz * sC;
    const float* rs = rsum + (long)bz * M;
    #pragma unroll
    for (int i = 0; i < 4; ++i) {
      const int rb = tileM + wm + i * 16 + lq * 4;
      float inv[4];
      #pragma unroll
      for (int r = 0; r < 4; ++r) inv[r] = 1.0f / rs[rb + r];
      #pragma unroll
      for (int j = 0; j < 4; ++j) {
        const int col = tileN + wn + j * 16 + lc;
        const float bv = bias[col];
        #pragma unroll
        for (int r = 0; r < 4; ++r)
          C[(long)(rb + r) * ldc + col] = acc[i][j][r] * inv[r] + bv;
      }
    }
  }
}

// ---------------------------------------------------------------------------
extern "C" void kernel_launch(void* const* d_in, const int* in_sizes, int n_in,
                              void* d_out, int out_size, void* d_ws, size_t ws_size,
                              hipStream_t stream) {
  const float* x    = (const float*)d_in[0];   // [B,S,D] fp32
  const float* W    = (const float*)d_in[1];   // [D,D]   fp32
  const float* bias = (const float*)d_in[2];   // [D]     fp32
  float* out        = (float*)d_out;           // [B,S,D] fp32
  (void)in_sizes; (void)n_in; (void)out_size; (void)ws_size;

  const int B = 8, S = 2048, D = 1024;
  const long BSD = (long)B * S * D;            // 16,777,216

  // workspace layout (u16 elements): ~162 MiB + 64 KiB row sums
  u16* Xb  = (u16*)d_ws;            // [B,S,D] bf16 (x)
  u16* XbT = Xb  + BSD;             // [B,D,S] bf16 (x transposed per batch)
  u16* Qb  = XbT + BSD;             // [B,S,D] bf16 (Q, pre-scaled by 1/32)
  u16* Wt  = Qb  + BSD;             // [D,D]   bf16 (W^T * 1/sqrt(D))
  u16* Sc  = Wt  + (long)D * D;     // [B,S,S] bf16 (E = exp(scores), unnorm)
  float* rsum = (float*)(Sc + (long)B * S * S);  // [B,S] fp32 row sums

  dim3 blk(256);

  // zero row sums (re-poisoned to 0xAA before every timed call)
  hipMemsetAsync(rsum, 0, (size_t)B * S * sizeof(float), stream);

  // x -> Xb + XbT (scale 1), W -> Wt (scale 1/32 folded into Q)
  cast_tr<<<dim3(D/64, S/64, B), blk, 0, stream>>>(x, Xb, XbT, S, D, 1.0f, (long)S*D);
  cast_tr<<<dim3(D/64, D/64, 1), blk, 0, stream>>>(W, nullptr, Wt, D, D, 0.03125f, 0);

  // GEMM1: Qb[BS,D] = Xb[BS,D] @ Wt[D,D]^T   (batches flattened)
  gemm_nt<0><<<dim3(D/128, (B*S)/128, 1), blk, 0, stream>>>(
      Xb, Wt, Qb, nullptr, nullptr, B*S, D, D, D, D, D, 0, 0, 0);

  // GEMM2: Sc[S,S] = exp(Qb[S,D] @ Xb[S,D]^T), rsum += row sums  per batch
  gemm_nt<1><<<dim3(S/128, S/128, B), blk, 0, stream>>>(
      Qb, Xb, Sc, nullptr, rsum, S, S, D, D, D, S,
      (long)S*D, (long)S*D, (long)S*S);

  // GEMM3: out[S,D] = (Sc/rsum)[S,S] @ XbT[D,S]^T + bias  per batch, fp32 out
  gemm_nt<2><<<dim3(D/128, S/128, B), blk, 0, stream>>>(
      Sc, XbT, out, bias, rsum, S, D, S, S, S, D,
      (long)S*S, (long)D*S, (long)S*D);
}